// Round 10
// baseline (246.357 us; speedup 1.0000x reference)
//
#include <hip/hip_runtime.h>

typedef __bf16 bf16_t;
typedef bf16_t bf16x8 __attribute__((ext_vector_type(8)));
typedef bf16_t bf16x4 __attribute__((ext_vector_type(4)));
typedef bf16_t bf16x2 __attribute__((ext_vector_type(2)));
typedef float f32x4 __attribute__((ext_vector_type(4)));
typedef float f32x16 __attribute__((ext_vector_type(16)));
typedef unsigned int u32x4 __attribute__((ext_vector_type(4)));

typedef const __attribute__((address_space(1))) void* as1_cvp;
typedef __attribute__((address_space(3))) void* as3_vp;

__device__ __forceinline__ void gload16(const void* g, void* l) {
  __builtin_amdgcn_global_load_lds((as1_cvp)g, (as3_vp)l, 16, 0, 0);
}

// partner (lane^32) value — unambiguous cross-lane primitive (verified r5-7)
__device__ __forceinline__ unsigned pxor32(unsigned x) {
  return (unsigned)__shfl_xor((int)x, 32);
}

// ---------------------------------------------------------------- convert f32 -> bf16
__global__ __launch_bounds__(256) void cvt_kernel(const float* __restrict__ src,
                                                  bf16_t* __restrict__ dst, int n8) {
  int i = blockIdx.x * 256 + threadIdx.x;
  if (i >= n8) return;
  int idx = i * 8;
  float4 a = *(const float4*)(src + idx);
  float4 b = *(const float4*)(src + idx + 4);
  bf16x8 o;
  o[0] = (bf16_t)a.x; o[1] = (bf16_t)a.y; o[2] = (bf16_t)a.z; o[3] = (bf16_t)a.w;
  o[4] = (bf16_t)b.x; o[5] = (bf16_t)b.y; o[6] = (bf16_t)b.z; o[7] = (bf16_t)b.w;
  *(bf16x8*)(dst + idx) = o;
}

#define BM 128
#define BN 128
#define BK 64

// ---------------------------------------------------------------- GEMM  C = A * B^T (f32 out)
__global__ __launch_bounds__(256, 2) void gemm_bt(const bf16_t* __restrict__ A,
                                                  const bf16_t* __restrict__ B,
                                                  float* __restrict__ C,
                                                  int M, int N, int K) {
  __shared__ alignas(16) bf16_t As[BM * BK];
  __shared__ alignas(16) bf16_t Bs[BN * BK];
  const int t = threadIdx.x;
  const int lane = t & 63, w = t >> 6;
  const int wm = w >> 1, wn = w & 1;
  const int lr = lane & 15, lg = lane >> 4;
  const int m0 = blockIdx.y * BM, n0 = blockIdx.x * BN;
  const int srow = t >> 3, scol = (t & 7) * 8;

  f32x4 acc[4][4] = {};

  for (int kb = 0; kb < K; kb += BK) {
    __syncthreads();
#pragma unroll
    for (int i = 0; i < 4; ++i) {
      gload16(A + (size_t)(m0 + srow + 32 * i) * K + kb + scol, As + i * 2048 + t * 8);
      gload16(B + (size_t)(n0 + srow + 32 * i) * K + kb + scol, Bs + i * 2048 + t * 8);
    }
    __syncthreads();
#pragma unroll
    for (int kk = 0; kk < 2; ++kk) {
      const int ko = kk * 32 + lg * 8;
      bf16x8 af[4], bfr[4];
#pragma unroll
      for (int r = 0; r < 4; ++r)
        af[r] = *(const bf16x8*)(As + (wm * 64 + r * 16 + lr) * BK + ko);
#pragma unroll
      for (int c = 0; c < 4; ++c)
        bfr[c] = *(const bf16x8*)(Bs + (wn * 64 + c * 16 + lr) * BK + ko);
#pragma unroll
      for (int r = 0; r < 4; ++r)
#pragma unroll
        for (int c = 0; c < 4; ++c)
          acc[r][c] = __builtin_amdgcn_mfma_f32_16x16x32_bf16(af[r], bfr[c], acc[r][c], 0, 0, 0);
    }
  }
#pragma unroll
  for (int r = 0; r < 4; ++r)
#pragma unroll
    for (int c = 0; c < 4; ++c)
#pragma unroll
      for (int b = 0; b < 4; ++b)
        C[(size_t)(m0 + wm * 64 + r * 16 + lg * 4 + b) * N + n0 + wn * 64 + c * 16 + lr] =
            acc[r][c][b];
}

// ---------------------------------------------------------------- fused QKV GEMM + RoPE + relayout
__global__ __launch_bounds__(256, 2) void gemm_qkv(const bf16_t* __restrict__ A,
                                                   const bf16_t* __restrict__ B,
                                                   const float* __restrict__ cs,
                                                   const float* __restrict__ sn,
                                                   bf16_t* __restrict__ qr,
                                                   bf16_t* __restrict__ kr,
                                                   bf16_t* __restrict__ vt) {
  __shared__ alignas(16) bf16_t As[BM * BK];
  __shared__ alignas(16) bf16_t Bs[BN * BK];
  const int K = 2048;
  const int t = threadIdx.x;
  const int lane = t & 63, w = t >> 6;
  const int wm = w >> 1, wn = w & 1;
  const int lr = lane & 15, lg = lane >> 4;
  const int m0 = blockIdx.y * BM, n0 = blockIdx.x * BN;
  const int srow = t >> 3, scol = (t & 7) * 8;

  f32x4 acc[4][4] = {};

  for (int kb = 0; kb < K; kb += BK) {
    __syncthreads();
#pragma unroll
    for (int i = 0; i < 4; ++i) {
      gload16(A + (size_t)(m0 + srow + 32 * i) * K + kb + scol, As + i * 2048 + t * 8);
      gload16(B + (size_t)(n0 + srow + 32 * i) * K + kb + scol, Bs + i * 2048 + t * 8);
    }
    __syncthreads();
#pragma unroll
    for (int kk = 0; kk < 2; ++kk) {
      const int ko = kk * 32 + lg * 8;
      bf16x8 af[4], bfr[4];
#pragma unroll
      for (int r = 0; r < 4; ++r)
        af[r] = *(const bf16x8*)(As + (wm * 64 + r * 16 + lr) * BK + ko);
#pragma unroll
      for (int c = 0; c < 4; ++c)
        bfr[c] = *(const bf16x8*)(Bs + (wn * 64 + c * 16 + lr) * BK + ko);
#pragma unroll
      for (int r = 0; r < 4; ++r)
#pragma unroll
        for (int c = 0; c < 4; ++c)
          acc[r][c] = __builtin_amdgcn_mfma_f32_16x16x32_bf16(af[r], bfr[c], acc[r][c], 0, 0, 0);
    }
  }

  // epilogue: D layout row=(lane>>4)*4+b, col=lane&15 within 16x16 frag
  const int head = n0 >> 7;               // one head per N-tile
  const int bb2 = m0 >> 11;               // batch
  const int sbase = (m0 & 2047) + wm * 64 + lg * 4;  // + r*16 + b -> token s
  if (head < 20) {
    bf16_t* dst = (head < 16) ? qr + (size_t)(bb2 * 16 + head) * 2048 * 128
                              : kr + (size_t)(bb2 * 4 + (head - 16)) * 2048 * 128;
    const bool evn = (lr & 1) == 0;
#pragma unroll
    for (int r = 0; r < 4; ++r)
#pragma unroll
      for (int c = 0; c < 4; ++c) {
        const int cw = wn * 64 + c * 16 + lr;   // within-head col
        const int dix = cw >> 1;
#pragma unroll
        for (int b = 0; b < 4; ++b) {
          const int s = sbase + r * 16 + b;
          float own = acc[r][c][b];
          float prt = __shfl_xor(own, 1);
          if (evn) {
            float cc = cs[s * 64 + dix];
            float ssn = sn[s * 64 + dix];
            bf16x2 pr;
            pr[0] = (bf16_t)(own * cc - prt * ssn);
            pr[1] = (bf16_t)(own * ssn + prt * cc);
            *(bf16x2*)(dst + (size_t)s * 128 + cw) = pr;
          }
        }
      }
  } else {
    bf16_t* dst = vt + (size_t)(bb2 * 4 + (head - 20)) * 128 * 2048;
#pragma unroll
    for (int r = 0; r < 4; ++r)
#pragma unroll
      for (int c = 0; c < 4; ++c) {
        const int cw = wn * 64 + c * 16 + lr;
        const int s = sbase + r * 16;
        bf16x4 v4;
#pragma unroll
        for (int b = 0; b < 4; ++b) v4[b] = (bf16_t)acc[r][c][b];
        *(bf16x4*)(dst + (size_t)cw * 2048 + s) = v4;
      }
  }
}

// ---------------------------------------------------------------- flash attention (32x32 MFMA)
// Q:(B,NH,S,HD) K:(B,NKV,S,HD) Vt:(B,NKV,HD,S) bf16 -> O:(B*S, H) bf16
// 4 waves/block, 32 q-rows/wave, QBLK=128, grid 512 = 2 blocks/CU.
// Swapped QK^T via mfma_32x32x16 -> q = lane&31; lane pair (l, l+32) holds
// disjoint k halves. ALL cross-lane ops via __shfl_xor(.,32) (unambiguous;
// r8/r9's permlane asm is the isolated suspect). P->A-frag exchange per
// 4-word group g: [hi? p2:W0, hi? p3:W1, hi? W2:p0, hi? W3:p1], p=partner.
// LDS chunk-major Ks[cc][key][8], Vs[cc][d][8] (conflict-free contiguous 16B
// fragment reads). K double-buffered, V single, 48KB LDS, 2 barriers/tile.
// T13 defer-rescale, T5 setprio, T1 XCD swizzle.
#define KVB 64
__global__ __launch_bounds__(256, 2) void attn_kernel(const bf16_t* __restrict__ Q,
                                                      const bf16_t* __restrict__ Kg,
                                                      const bf16_t* __restrict__ Vg,
                                                      bf16_t* __restrict__ O) {
  __shared__ alignas(16) bf16_t Ks[2][16 * KVB * 8];  // [cc=d-chunk][key][8elem] 16KB x2
  __shared__ alignas(16) bf16_t Vs[8 * 128 * 8];      // [cc=key-chunk][d][8elem] 16KB
  const int t = threadIdx.x;
  const int lane = t & 63, w = t >> 6;
  const int l31 = lane & 31, hi = lane >> 5;
  // XCD-aware bijective swizzle (512 % 8 == 0): each XCD owns one (bb,kvh)
  const int bid = ((blockIdx.x & 7) << 6) | (blockIdx.x >> 3);
  const int qt = bid & 15;          // 16 q-tiles of 128 rows
  const int h = (bid >> 4) & 15;
  const int bb = bid >> 8;
  const int kvh = h >> 2;

  const bf16_t* Qh = Q + (((size_t)bb * 16 + h) * 2048 + qt * 128 + w * 32) * 128;
  const bf16_t* Kh = Kg + ((size_t)bb * 4 + kvh) * 2048 * 128;
  const bf16_t* Vh = Vg + ((size_t)bb * 4 + kvh) * 128 * 2048;

  // hoist Q fragments: B-frag of swapped QK^T: lane holds Q[q=l31][c*16+hi*8+j]
  bf16x8 qf[8];
#pragma unroll
  for (int c = 0; c < 8; ++c)
    qf[c] = *(const bf16x8*)(Qh + l31 * 128 + c * 16 + hi * 8);

  f32x16 o[4] = {};            // O[q=(r&3)+8*(r>>2)+4*hi][d=dblk*32+l31]
  float m2 = -1e30f;           // running max of row q=l31 (synced across pair)
  float ls = 0.f;              // per-lane partial sum (this lane's 32 k-slots)
  const float sm = 0.08838834764831845f * 1.44269504088896f;  // 1/sqrt(128)*log2(e)

  // staging: chunk-major linear LDS dest (wave-uniform + lane*16), strided gsrc
#define STAGE_K(buf, kb)                                                                \
  _Pragma("unroll") for (int i = 0; i < 4; ++i)                                         \
    gload16(Kh + (size_t)((kb) + (t & 63)) * 128 + (i * 4 + (t >> 6)) * 8,              \
            &Ks[buf][(i * 256 + t) * 8]);
#define STAGE_V(kb)                                                                     \
  _Pragma("unroll") for (int i = 0; i < 4; ++i)                                         \
    gload16(Vh + (size_t)(t & 127) * 2048 + (kb) + (i * 2 + (t >> 7)) * 8,              \
            &Vs[(i * 256 + t) * 8]);

  STAGE_K(0, 0);
  __syncthreads();  // K(0) ready

  for (int tt = 0; tt < 32; ++tt) {
    const int cur = tt & 1;
    STAGE_V(tt * KVB);                                  // V(t): covered by QK^T+softmax
    if (tt < 31) { STAGE_K(cur ^ 1, (tt + 1) * KVB); }  // K(t+1): covered by full tile
    const bf16_t* Kc = Ks[cur];

    // a) swapped QK^T: D[key][q]; lane holds P[q=l31][k=kblk*32+(r&3)+8*(r>>2)+4*hi]
    f32x16 s0 = {}, s1 = {};
    __builtin_amdgcn_s_setprio(1);
#pragma unroll
    for (int c = 0; c < 8; ++c) {
      bf16x8 kf0 = *(const bf16x8*)(Kc + ((c * 2 + hi) * 64 + l31) * 8);
      bf16x8 kf1 = *(const bf16x8*)(Kc + ((c * 2 + hi) * 64 + 32 + l31) * 8);
      s0 = __builtin_amdgcn_mfma_f32_32x32x16_bf16(kf0, qf[c], s0, 0, 0, 0);
      s1 = __builtin_amdgcn_mfma_f32_32x32x16_bf16(kf1, qf[c], s1, 0, 0, 0);
    }
    __builtin_amdgcn_s_setprio(0);
    s0 = s0 * sm;  // log2 units
    s1 = s1 * sm;

    // b) in-register online softmax; row q=l31 lives in lane pair (l, l+32)
    float tm[8];
#pragma unroll
    for (int j = 0; j < 8; ++j)
      tm[j] = fmaxf(fmaxf(s0[2 * j], s0[2 * j + 1]), fmaxf(s1[2 * j], s1[2 * j + 1]));
    float mx = fmaxf(fmaxf(fmaxf(tm[0], tm[1]), fmaxf(tm[2], tm[3])),
                     fmaxf(fmaxf(tm[4], tm[5]), fmaxf(tm[6], tm[7])));
    mx = fmaxf(mx, __shfl_xor(mx, 32));   // pair-combine -> full row max

    if (__any(mx > m2 + 8.0f)) {  // T13 defer-rescale (rare)
      float mn = fmaxf(m2, mx);
      float resc = exp2f(m2 - mn);
      m2 = mn;
      ls *= resc;
      float rf[16];
#pragma unroll
      for (int r = 0; r < 16; ++r) rf[r] = __shfl(resc, (r & 3) + 8 * (r >> 2) + 4 * hi);
#pragma unroll
      for (int dblk = 0; dblk < 4; ++dblk)
#pragma unroll
        for (int r = 0; r < 16; ++r) o[dblk][r] *= rf[r];
    }
#pragma unroll
    for (int r = 0; r < 16; ++r) {
      float p0 = exp2f(s0[r] - m2);
      float p1 = exp2f(s1[r] - m2);
      s0[r] = p0; s1[r] = p1;
      ls += p0 + p1;
    }

    // pack pairs: W[s] = {P(reg 2s), P(reg 2s+1)} = adjacent keys, even key low
    unsigned Wa[8], Wb[8];
#pragma unroll
    for (int s = 0; s < 8; ++s) {
      bf16x2 a = {(bf16_t)s0[2 * s], (bf16_t)s0[2 * s + 1]};
      bf16x2 b = {(bf16_t)s1[2 * s], (bf16_t)s1[2 * s + 1]};
      Wa[s] = __builtin_bit_cast(unsigned, a);
      Wb[s] = __builtin_bit_cast(unsigned, b);
    }
    // exchange via shfl_xor(32): own keys (hi=0): {0,1},{2,3},{8,9},{10,11},... ;
    // partner holds the complementary 8-key groups. A-frag word m of the 16-key
    // group needs keys {base+2m, base+2m+1} with base = kk*16 + hi*8.
    bf16x8 pf[4];
    {
      unsigned wv[16];
#pragma unroll
      for (int g = 0; g < 4; ++g) {     // g: Wa-lo, Wa-hi, Wb-lo, Wb-hi
        unsigned* W = (g & 2) ? Wb : Wa;
        const int o4 = (g & 1) * 4;
        unsigned pp0 = pxor32(W[o4 + 0]);
        unsigned pp1 = pxor32(W[o4 + 1]);
        unsigned pp2 = pxor32(W[o4 + 2]);
        unsigned pp3 = pxor32(W[o4 + 3]);
        wv[g * 4 + 0] = hi ? pp2 : W[o4 + 0];
        wv[g * 4 + 1] = hi ? pp3 : W[o4 + 1];
        wv[g * 4 + 2] = hi ? W[o4 + 2] : pp0;
        wv[g * 4 + 3] = hi ? W[o4 + 3] : pp1;
      }
      u32x4 pw0 = {wv[0], wv[1], wv[2], wv[3]};
      u32x4 pw1 = {wv[4], wv[5], wv[6], wv[7]};
      u32x4 pw2 = {wv[8], wv[9], wv[10], wv[11]};
      u32x4 pw3 = {wv[12], wv[13], wv[14], wv[15]};
      pf[0] = __builtin_bit_cast(bf16x8, pw0);  // keys  0..15
      pf[1] = __builtin_bit_cast(bf16x8, pw1);  // keys 16..31
      pf[2] = __builtin_bit_cast(bf16x8, pw2);  // keys 32..47
      pf[3] = __builtin_bit_cast(bf16x8, pw3);  // keys 48..63
    }

    __syncthreads();  // c) QK^T reads done; V(t) and K(t+1) arrived (vmcnt drain)

    // d) PV: o[dblk] = sum_k P[q][k] V[k][d]; vf from chunk-major Vs
    __builtin_amdgcn_s_setprio(1);
#pragma unroll
    for (int kk = 0; kk < 4; ++kk) {
#pragma unroll
      for (int dblk = 0; dblk < 4; ++dblk) {
        bf16x8 vf = *(const bf16x8*)(Vs + ((kk * 2 + hi) * 128 + dblk * 32 + l31) * 8);
        o[dblk] = __builtin_amdgcn_mfma_f32_32x32x16_bf16(pf[kk], vf, o[dblk], 0, 0, 0);
      }
    }
    __builtin_amdgcn_s_setprio(0);
    __syncthreads();  // e) PV done -> Vs writable next tile
  }

  // epilogue: total l per row, divide, write (B*S, H) bf16
  float lt = ls + __shfl_xor(ls, 32);
  float rinv = 1.0f / lt;
  float rq[16];
#pragma unroll
  for (int r = 0; r < 16; ++r) rq[r] = __shfl(rinv, (r & 3) + 8 * (r >> 2) + 4 * hi);
  const size_t q0 = (size_t)bb * 2048 + qt * 128 + w * 32;
#pragma unroll
  for (int dblk = 0; dblk < 4; ++dblk)
#pragma unroll
    for (int r = 0; r < 16; ++r) {
      const int qrow = (r & 3) + 8 * (r >> 2) + 4 * hi;
      O[(q0 + qrow) * 2048 + h * 128 + dblk * 32 + l31] = (bf16_t)(o[dblk][r] * rq[r]);
    }
}

// ---------------------------------------------------------------- launch
extern "C" void kernel_launch(void* const* d_in, const int* in_sizes, int n_in,
                              void* d_out, int out_size, void* d_ws, size_t ws_size,
                              hipStream_t stream) {
  const float* hs = (const float*)d_in[0];
  const float* fc = (const float*)d_in[1];
  const float* fs = (const float*)d_in[2];
  const float* Wq = (const float*)d_in[3];
  const float* Wk = (const float*)d_in[4];
  const float* Wv = (const float*)d_in[5];
  const float* Wo = (const float*)d_in[6];
  float* out = (float*)d_out;

  char* ws = (char*)d_ws;
  bf16_t* hs_b = (bf16_t*)ws;                      // 16,777,216 B
  bf16_t* wcat = (bf16_t*)(ws + 16777216);         // 12,582,912 B (3072x2048)
  bf16_t* wo_b = (bf16_t*)(ws + 29360128);         //  8,388,608 B
  bf16_t* qr = (bf16_t*)(ws + 37748736);           // 16,777,216 B (B,16,S,128)
  bf16_t* kr = (bf16_t*)(ws + 54525952);           //  4,194,304 B (B,4,S,128)
  bf16_t* vt = (bf16_t*)(ws + 58720256);           //  4,194,304 B (B,4,128,S)
  bf16_t* ao = (bf16_t*)(ws + 62914560);           // 16,777,216 B  (total ~76 MB)

  cvt_kernel<<<8388608 / 8 / 256, 256, 0, stream>>>(hs, hs_b, 8388608 / 8);
  cvt_kernel<<<4194304 / 8 / 256, 256, 0, stream>>>(Wq, wcat, 4194304 / 8);
  cvt_kernel<<<1048576 / 8 / 256, 256, 0, stream>>>(Wk, wcat + 4194304, 1048576 / 8);
  cvt_kernel<<<1048576 / 8 / 256, 256, 0, stream>>>(Wv, wcat + 5242880, 1048576 / 8);
  cvt_kernel<<<4194304 / 8 / 256, 256, 0, stream>>>(Wo, wo_b, 4194304 / 8);

  dim3 g1(3072 / BN, 4096 / BM);
  gemm_qkv<<<g1, 256, 0, stream>>>(hs_b, wcat, fc, fs, qr, kr, vt);

  attn_kernel<<<512, 256, 0, stream>>>(qr, kr, vt, ao);

  dim3 g2(2048 / BN, 4096 / BM);
  gemm_bt<<<g2, 256, 0, stream>>>(ao, wo_b, out, 4096, 2048, 2048);
}